// Round 6
// baseline (124.959 us; speedup 1.0000x reference)
//
#include <hip/hip_runtime.h>

#define B_ 2
#define L_ 256
#define D_ 512
#define H_ 8
#define DV_ 64
#define NEGINF 1e12f

// ws layout (floats):
#define WS_VALUE 0          // [B*H][L][DV]  = 262144
#define WS_WR    262144     // [512][8]      = 4096
#define WS_SSRC  266240     // [B*H][L]      = 4096
#define WS_STGT  270336     // [B*H][L]      = 4096
#define WS_SREL  274432     // [bi][h][j]    = 512*2048 = 1048576

// ---------------- Kernel A: WR[k][h] = sum_d W_relation[k][h*64+d] * w_rel[h][d]
__global__ __launch_bounds__(256) void k_wr(const float* __restrict__ Wrel,
                                            const float* __restrict__ wrel,
                                            float* __restrict__ WR) {
    int flat = blockIdx.x * 256 + threadIdx.x;   // 4096 = 512*8
    int k = flat >> 3, h = flat & 7;
    const float* a = Wrel + k * 512 + h * 64;
    const float* b = wrel + h * 64;
    float s = 0.f;
#pragma unroll
    for (int d = 0; d < 64; d += 4) {
        float4 x = *(const float4*)(a + d);
        float4 y = *(const float4*)(b + d);
        s += x.x * y.x + x.y * y.y + x.z * y.z + x.w * y.w;
    }
    WR[k * 8 + h] = s;
}

// ---------------- Kernel B: value = inp @ W_value, + fused s_src/s_tgt epilogue
__global__ __launch_bounds__(256) void k_value(const float* __restrict__ inp,
                                               const float* __restrict__ Wv,
                                               const float* __restrict__ wsrc,
                                               const float* __restrict__ wtgt,
                                               float* __restrict__ value,
                                               float* __restrict__ s_src,
                                               float* __restrict__ s_tgt) {
    int blk = blockIdx.x;          // 256 blocks = 128 row-tiles x 2 col-halves
    int ct  = blk & 1;
    int rt  = blk >> 1;
    int n   = ct * 256 + threadIdx.x;   // output col 0..511
    int r0  = rt * 4;
    const float* i0 = inp + (size_t)(r0 + 0) * 512;
    const float* i1 = inp + (size_t)(r0 + 1) * 512;
    const float* i2 = inp + (size_t)(r0 + 2) * 512;
    const float* i3 = inp + (size_t)(r0 + 3) * 512;
    float a0 = 0.f, a1 = 0.f, a2 = 0.f, a3 = 0.f;
#pragma unroll 16
    for (int k = 0; k < 512; ++k) {
        float w = Wv[(size_t)k * 512 + n];
        a0 = fmaf(i0[k], w, a0);
        a1 = fmaf(i1[k], w, a1);
        a2 = fmaf(i2[k], w, a2);
        a3 = fmaf(i3[k], w, a3);
    }
    int h = n >> 6, dv = n & 63;
    float acc[4] = {a0, a1, a2, a3};
    float wsv = wsrc[h * 64 + dv];
    float wtv = wtgt[h * 64 + dv];
#pragma unroll
    for (int r = 0; r < 4; ++r) {
        int row = r0 + r;
        int b = row >> 8, l = row & 255;
        value[(((size_t)(b * 8 + h)) * 256 + l) * 64 + dv] = acc[r];
        float ss = acc[r] * wsv;
        float st = acc[r] * wtv;
#pragma unroll
        for (int off = 32; off >= 1; off >>= 1) {
            ss += __shfl_xor(ss, off);
            st += __shfl_xor(st, off);
        }
        if (dv == 0) {
            s_src[(size_t)(b * 8 + h) * 256 + l] = ss;
            s_tgt[(size_t)(b * 8 + h) * 256 + l] = st;
        }
    }
}

// ---------------- Kernel C: srel[bi][h][j] = rel[row=bi*256+j, :] . WR[:, h]
// One WAVE per row batch: wave owns 32 rows; per row, lane l loads float4 at
// floats {4l..4l+3} and {256+4l..}: one VMEM instr = 1 KB contiguous.
// Weights for lane l are contiguous: WR[32l..32l+32) and WR[2048+32l..).
// Reduce: butterfly bits 3,4,5 on all 8 accs; select A[lane>>3]; butterfly
// bits 0,1,2; lanes l%8==0 hold Total[l>>3]. No LDS, no barriers.
__global__ __launch_bounds__(256, 3) void k_srel(const float* __restrict__ rel,
                                                 const float* __restrict__ WR,
                                                 float* __restrict__ srel) {
    int tid  = threadIdx.x;
    int lane = tid & 63;
    int gw   = blockIdx.x * 4 + (tid >> 6);     // 0..4095, 32 rows each

    // preload weights: wa[i]=WR[32l+i], wb[i]=WR[2048+32l+i]
    float wa[32], wb[32];
    {
        const float4* wp = (const float4*)(WR + 32 * lane);
        const float4* wq = (const float4*)(WR + 2048 + 32 * lane);
#pragma unroll
        for (int s = 0; s < 8; ++s) {
            float4 t = wp[s];
            wa[4 * s] = t.x; wa[4 * s + 1] = t.y; wa[4 * s + 2] = t.z; wa[4 * s + 3] = t.w;
            float4 u = wq[s];
            wb[4 * s] = u.x; wb[4 * s + 1] = u.y; wb[4 * s + 2] = u.z; wb[4 * s + 3] = u.w;
        }
    }

    const float* rp = rel + (size_t)gw * 32 * 512 + lane * 4;

#define LOADLO(j) (*(const float4*)(rp + (size_t)(j) * 512))
#define LOADHI(j) (*(const float4*)(rp + (size_t)(j) * 512 + 256))

#define ROW(lo, hi, jj)                                                        \
    {                                                                          \
        float A[8];                                                            \
        _Pragma("unroll")                                                      \
        for (int h = 0; h < 8; ++h) {                                          \
            A[h] = fmaf(lo.x, wa[h],                                           \
                   fmaf(lo.y, wa[8 + h],                                       \
                   fmaf(lo.z, wa[16 + h],                                      \
                   fmaf(lo.w, wa[24 + h],                                      \
                   fmaf(hi.x, wb[h],                                           \
                   fmaf(hi.y, wb[8 + h],                                       \
                   fmaf(hi.z, wb[16 + h],                                      \
                        hi.w * wb[24 + h])))))));                              \
        }                                                                      \
        _Pragma("unroll")                                                      \
        for (int h = 0; h < 8; ++h) {                                          \
            A[h] += __shfl_xor(A[h], 8);                                       \
            A[h] += __shfl_xor(A[h], 16);                                      \
            A[h] += __shfl_xor(A[h], 32);                                      \
        }                                                                      \
        int hi3 = lane >> 3;                                                   \
        float v = A[0];                                                        \
        _Pragma("unroll")                                                      \
        for (int h = 1; h < 8; ++h) v = (hi3 == h) ? A[h] : v;                 \
        v += __shfl_xor(v, 1);                                                 \
        v += __shfl_xor(v, 2);                                                 \
        v += __shfl_xor(v, 4);                                                 \
        if ((lane & 7) == 0) {                                                 \
            int R = gw * 32 + (jj);                                            \
            srel[((size_t)(R >> 8)) * 2048 + hi3 * 256 + (R & 255)] = v;       \
        }                                                                      \
    }

    float4 loA = LOADLO(0), hiA = LOADHI(0);
    float4 loB = LOADLO(1), hiB = LOADHI(1);
#pragma unroll 1
    for (int jj = 0; jj < 32; jj += 2) {
        float4 nloA, nhiA, nloB, nhiB;
        if (jj + 2 < 32) { nloA = LOADLO(jj + 2); nhiA = LOADHI(jj + 2); }
        if (jj + 3 < 32) { nloB = LOADLO(jj + 3); nhiB = LOADHI(jj + 3); }
        ROW(loA, hiA, jj);
        ROW(loB, hiB, jj + 1);
        loA = nloA; hiA = nhiA; loB = nloB; hiB = nhiB;
    }
#undef ROW
#undef LOADLO
#undef LOADHI
}

// ---------------- Kernel E: softmax + PV + residual. Block = one (b,i).
__global__ __launch_bounds__(256) void k_attn(const int*   __restrict__ mask,   // [bi][j]
                                              const float* __restrict__ adj,    // [b][h][i][j]
                                              const float* __restrict__ inp,    // [bi][D]
                                              const float* __restrict__ value,  // [b][h][j][dv]
                                              const float* __restrict__ srel,   // [bi][h][j]
                                              const float* __restrict__ s_src,  // [b][h][j]
                                              const float* __restrict__ s_tgt,  // [b][h][i]
                                              float* __restrict__ out) {        // [bi][D]
    __shared__ float attn_s[2048];     // [h][j]
    int bi  = blockIdx.x;
    int b   = bi >> 8;
    int i   = bi & 255;
    int tid = threadIdx.x;

    // ---- softmax: 32 lanes per h, 8 j per lane
    {
        int h  = tid >> 5;
        int ln = tid & 31;
        float stgt = s_tgt[(size_t)(b * 8 + h) * 256 + i];
        const float* ssrc   = s_src + (size_t)(b * 8 + h) * 256;
        const float* srl    = srel + (size_t)bi * 2048 + h * 256;
        const float* adjrow = adj + ((size_t)(b * 8 + h) * 256 + i) * 256;
        const int*   mrow   = mask + (size_t)bi * 256;

        float sc[8], av[8];
        int mb = 0;
        float rowmax = -3.0e38f;
#pragma unroll
        for (int t = 0; t < 8; ++t) {
            int j = ln + 32 * t;
            float a = adjrow[j];
            av[t] = a;
            int m = mrow[j];
            float s = ssrc[j] + stgt + srl[j];
            s = (s >= 0.f) ? s : 0.2f * s;     // leaky relu
            if (m != 0) { s = -NEGINF; mb |= (1 << t); }
            if (a == 0.f) s = -NEGINF;
            sc[t] = s;
            rowmax = fmaxf(rowmax, s);
        }
#pragma unroll
        for (int off = 16; off >= 1; off >>= 1)
            rowmax = fmaxf(rowmax, __shfl_xor(rowmax, off));

        float rowsum = 0.f;
#pragma unroll
        for (int t = 0; t < 8; ++t) {
            sc[t] = expf(sc[t] - rowmax);
            rowsum += sc[t];
        }
#pragma unroll
        for (int off = 16; off >= 1; off >>= 1)
            rowsum += __shfl_xor(rowsum, off);
        float rinv = 1.0f / rowsum;

        float sumabs = 0.f;
#pragma unroll
        for (int t = 0; t < 8; ++t) {
            float p = sc[t] * rinv;
            float invv = (av[t] == 0.f) ? 1e-12f : (1.0f / av[t]);
            p *= invv;
            sc[t] = p;
            sumabs += fabsf(p);
        }
#pragma unroll
        for (int off = 16; off >= 1; off >>= 1)
            sumabs += __shfl_xor(sumabs, off);

        float rdn = 1.0f / fmaxf(sumabs, 1e-12f);
#pragma unroll
        for (int t = 0; t < 8; ++t) {
            float p = sc[t] * rdn;
            if (mb & (1 << t)) p = 0.f;
            if (av[t] == 0.f) p = 0.f;
            attn_s[h * 256 + ln + 32 * t] = p;
        }
    }
    __syncthreads();

    // ---- PV: out[bi][h*64+d] = inp + sum_j attn[h][j] * value[b][h][j][d]
    {
        int h  = tid >> 5;
        int d0 = (tid & 31) * 2;
        const float* vbase = value + ((size_t)(b * 8 + h) * 256) * 64 + d0;
        const float* arow  = attn_s + h * 256;
        float ax = 0.f, ay = 0.f;
#pragma unroll 8
        for (int j = 0; j < 256; ++j) {
            float a = arow[j];
            float2 v2 = *(const float2*)(vbase + (size_t)j * 64);
            ax = fmaf(a, v2.x, ax);
            ay = fmaf(a, v2.y, ay);
        }
        size_t o = (size_t)bi * 512 + h * 64 + d0;
        out[o]     = inp[o] + ax;
        out[o + 1] = inp[o + 1] + ay;
    }
}

extern "C" void kernel_launch(void* const* d_in, const int* in_sizes, int n_in,
                              void* d_out, int out_size, void* d_ws, size_t ws_size,
                              hipStream_t stream) {
    const float* inp      = (const float*)d_in[0];
    const float* rel      = (const float*)d_in[1];
    const int*   mask     = (const int*)  d_in[2];
    const float* adj      = (const float*)d_in[3];
    const float* W_value  = (const float*)d_in[4];
    const float* W_rel    = (const float*)d_in[5];
    const float* w_src    = (const float*)d_in[6];
    const float* w_tgt    = (const float*)d_in[7];
    const float* w_rel    = (const float*)d_in[8];
    float* out = (float*)d_out;

    float* ws    = (float*)d_ws;
    float* value = ws + WS_VALUE;
    float* WR    = ws + WS_WR;
    float* s_src = ws + WS_SSRC;
    float* s_tgt = ws + WS_STGT;
    float* srel  = ws + WS_SREL;

    k_wr<<<16, 256, 0, stream>>>(W_rel, w_rel, WR);
    k_srel<<<1024, 256, 0, stream>>>(rel, WR, srel);
    k_value<<<256, 256, 0, stream>>>(inp, W_value, w_src, w_tgt,
                                     value, s_src, s_tgt);
    k_attn<<<B_ * L_, 256, 0, stream>>>(mask, adj, inp, value, srel,
                                        s_src, s_tgt, out);
}